// Round 6
// baseline (210.333 us; speedup 1.0000x reference)
//
#include <hip/hip_runtime.h>
#include <math.h>

#define T_SEQ 2048
#define DIM   1024
#define HD3   3072
#define NH    16
#define HD    64
#define EPSF  1e-4f
#define MB    1048576

typedef __attribute__((ext_vector_type(8))) short bf16x8;
typedef __attribute__((ext_vector_type(4))) float f32x4;
typedef __attribute__((ext_vector_type(16))) float f32x16;
typedef __attribute__((ext_vector_type(4))) unsigned int u32x4;

__device__ __forceinline__ ushort f2bf(float f) {
  unsigned int u = __float_as_uint(f);
  unsigned int r = (u + 0x7FFFu + ((u >> 16) & 1u)) >> 16;
  return (ushort)r;
}
__device__ __forceinline__ float bf2f(ushort u) {
  return __uint_as_float(((unsigned int)u) << 16);
}

#define GLOAD(gp, lp) __builtin_amdgcn_global_load_lds( \
    (const __attribute__((address_space(1))) unsigned int*)(gp), \
    (__attribute__((address_space(3))) unsigned int*)(lp), 16, 0, 0)

// ---------- helpers ----------
__device__ __forceinline__ float blockSum(float v, float* s4) {
#pragma unroll
  for (int o = 32; o > 0; o >>= 1) v += __shfl_xor(v, o, 64);
  __syncthreads();
  if ((threadIdx.x & 63) == 0) s4[threadIdx.x >> 6] = v;
  __syncthreads();
  return s4[0] + s4[1] + s4[2] + s4[3];
}

// ---------- 0) f32 -> bf16 convert ----------
__global__ void cvt_kernel(const float* __restrict__ src, ushort* __restrict__ dst, int n8) {
  int i = blockIdx.x * 256 + threadIdx.x;
  if (i >= n8) return;
  float4 a = ((const float4*)src)[i * 2];
  float4 b = ((const float4*)src)[i * 2 + 1];
  bf16x8 v;
  v[0] = f2bf(a.x); v[1] = f2bf(a.y); v[2] = f2bf(a.z); v[3] = f2bf(a.w);
  v[4] = f2bf(b.x); v[5] = f2bf(b.y); v[6] = f2bf(b.z); v[7] = f2bf(b.w);
  *(bf16x8*)(dst + (size_t)i * 8) = v;
}

// ---------- 1) logmap(ref, x) -> bf16 xhyp ; also emit ref (f32) ----------
__global__ void logmap_kernel(const float* __restrict__ x,
                              ushort* __restrict__ xhyp,
                              float* __restrict__ ref_out) {
  __shared__ float s4[4];
  int t = blockIdx.x;
  const float* xt = x + (size_t)t * DIM;
  float xe[4], re[4];
  float xn2 = 0.f, yn2 = 0.f, ip = 0.f;
#pragma unroll
  for (int i = 0; i < 4; i++) {
    int e = threadIdx.x + i * 256;
    float xv = xt[e];
    float rv = (t > 0) ? xt[e - DIM] : 0.f;
    xe[i] = xv; re[i] = rv;
    yn2 += xv * xv;
    xn2 += rv * rv;
    ip  -= rv * xv;
    ref_out[(size_t)t * DIM + e] = rv;
  }
  xn2 = blockSum(xn2, s4);
  yn2 = blockSum(yn2, s4);
  ip  = blockSum(ip,  s4);
  float a = 1.f + 2.f * ip + yn2;
  float b = 1.f - xn2;
  float den = fmaxf(1.f + 2.f * ip + xn2 * yn2, EPSF);
  float invden = 1.f / den;
  float mob[4];
  float mn2 = 0.f;
#pragma unroll
  for (int i = 0; i < 4; i++) {
    float m = (-a * re[i] + b * xe[i]) * invden;
    mob[i] = m;
    mn2 += m * m;
  }
  mn2 = blockSum(mn2, s4);
  float mn  = sqrtf(mn2);
  float sf  = 2.f / (1.f + xn2);
  float cf  = 2.f / (sf + EPSF);
  float arg = fminf(sqrtf(mn), 0.99f);
  float mult = cf * atanhf(arg) / (mn + EPSF);
#pragma unroll
  for (int i = 0; i < 4; i++)
    xhyp[(size_t)t * DIM + threadIdx.x + i * 256] = f2bf(mult * mob[i]);
}

// ---------- 2/5) C[M][N] = A[M][K] * W[N][K]^T  (bf16 MFMA, f32 out) ----------
__global__ __launch_bounds__(256) void gemm_bf16(const ushort* __restrict__ A,
                                                 const ushort* __restrict__ W,
                                                 float* __restrict__ C,
                                                 int M, int N, int K) {
  __shared__ ushort As[128 * 32];
  __shared__ ushort Bs[128 * 32];
  int tid = threadIdx.x;
  int lane = tid & 63, w = tid >> 6;
  int wr = w >> 1, wc = w & 1;
  int g = lane >> 4, cc = lane & 15;
  int bm = blockIdx.y * 128, bn = blockIdx.x * 128;
  f32x4 acc[4][4] = {};
  for (int kt = 0; kt < K; kt += 32) {
#pragma unroll
    for (int i = 0; i < 2; i++) {
      int ch = (w * 2 + i) * 64 + lane;
      int row = ch >> 2, c8 = (ch & 3) * 8;
      GLOAD(A + (size_t)(bm + row) * K + kt + c8, &As[(w * 2 + i) * 512]);
      GLOAD(W + (size_t)(bn + row) * K + kt + c8, &Bs[(w * 2 + i) * 512]);
    }
    __syncthreads();
    bf16x8 af[4], bfr[4];
#pragma unroll
    for (int m = 0; m < 4; m++)
      af[m] = *(const bf16x8*)&As[(wr * 64 + m * 16 + cc) * 32 + 8 * g];
#pragma unroll
    for (int n = 0; n < 4; n++)
      bfr[n] = *(const bf16x8*)&Bs[(wc * 64 + n * 16 + cc) * 32 + 8 * g];
#pragma unroll
    for (int m = 0; m < 4; m++)
#pragma unroll
      for (int n = 0; n < 4; n++)
        acc[m][n] = __builtin_amdgcn_mfma_f32_16x16x32_bf16(af[m], bfr[n], acc[m][n], 0, 0, 0);
    __syncthreads();
  }
#pragma unroll
  for (int m = 0; m < 4; m++)
#pragma unroll
    for (int n = 0; n < 4; n++)
#pragma unroll
      for (int j = 0; j < 4; j++)
        C[(size_t)(bm + wr * 64 + m * 16 + g * 4 + j) * N + bn + wc * 64 + n * 16 + cc] = acc[m][n][j];
}

// ---------- 3) RMS-norm + rotary -> bf16 q,k in [h][t][64] ----------
__global__ void rmsrot_kernel(const float* __restrict__ qkv,
                              ushort* __restrict__ qb,
                              ushort* __restrict__ kb) {
  int t = blockIdx.x;
  int w = threadIdx.x >> 6;
  int lane = threadIdx.x & 63;
  int h = blockIdx.y * 4 + w;
  const float* base = qkv + (size_t)t * HD3;
  float qv = base[h * HD + lane];
  float kv = base[DIM + h * HD + lane];
  float qs = qv * qv, ks = kv * kv;
#pragma unroll
  for (int o = 32; o > 0; o >>= 1) {
    qs += __shfl_xor(qs, o, 64);
    ks += __shfl_xor(ks, o, 64);
  }
  float qn = qv * rsqrtf(qs * (1.f / 64.f) + 1.1920929e-07f);
  float kn = kv * rsqrtf(ks * (1.f / 64.f) + 1.1920929e-07f);
  int j = lane & 31;
  float cth = 1.f, sth = 0.f;
  if (j < 16) {
    float freq = exp2f(-(10.f / 15.f) * (float)j);
    float th = (float)t * freq;
    cth = cosf(th);
    sth = sinf(th);
  }
  float qp = __shfl_xor(qn, 32, 64);
  float kp = __shfl_xor(kn, 32, 64);
  float sgn = (lane < 32) ? 1.f : -1.f;
  float qr = qn * cth + sgn * qp * sth;
  float kr = kn * cth + sgn * kp * sth;
  qb[((size_t)h * T_SEQ + t) * HD + lane] = f2bf(qr);
  kb[((size_t)h * T_SEQ + t) * HD + lane] = f2bf(kr);
}

// ---------- 3b) V transpose -> bf16 vT [h][64][T] ----------
__global__ void vtrans_kernel(const float* __restrict__ qkv, ushort* __restrict__ vt) {
  __shared__ ushort tile[64][68];
  int h = blockIdx.y, tt = blockIdx.x;
  int d = threadIdx.x & 63, tr = threadIdx.x >> 6;
#pragma unroll
  for (int i = 0; i < 16; i++) {
    int t = tt * 64 + tr + i * 4;
    tile[d][tr + i * 4] = f2bf(qkv[(size_t)t * HD3 + 2 * DIM + h * HD + d]);
  }
  __syncthreads();
  int td = threadIdx.x & 63, dr = threadIdx.x >> 6;
#pragma unroll
  for (int i = 0; i < 16; i++) {
    int dd = dr + i * 4;
    vt[((size_t)h * HD + dd) * T_SEQ + tt * 64 + td] = tile[dd][td];
  }
}

// ---------- 4) causal flash attention, swapped-operand 32x32 MFMA, no LDS ----------
// Only verified primitives: __shfl_xor cross-lane, integer bf16 pack, mfma with
// consistent A/B fragment conventions, verified C/D row map.
// C[key][query]: col=lane&31=query, row=(reg&3)+8*(reg>>2)+4*(lane>>5)=key.
__global__ __launch_bounds__(256) void attn_mfma(const ushort* __restrict__ qb,
                                                 const ushort* __restrict__ kb,
                                                 const ushort* __restrict__ vt,
                                                 ushort* __restrict__ parts) {
  int lane = threadIdx.x & 63;
  int hi = lane >> 5;
  int q31 = lane & 31;
  int w = threadIdx.x >> 6;
  int tid = blockIdx.x * 4 + w;
  int h = tid / 160;
  int s = 159 - (tid % 160);      // heavy tasks first
  int qt, ch;
  if (s < 16)      { qt = s;                 ch = 0; }
  else if (s < 48) { qt = 16 + (s - 16) / 2; ch = (s - 16) % 2; }
  else if (s < 96) { qt = 32 + (s - 48) / 3; ch = (s - 48) % 3; }
  else             { qt = 48 + (s - 96) / 4; ch = (s - 96) % 4; }
  int qbase  = qt * 32;
  int kstart = ch * 512;
  int kend   = min(kstart + 512, qbase + 32);
  bool fin   = (kend == qbase + 32);
  int ntile  = (kend - kstart) >> 5;

  const ushort* qh = qb + (size_t)h * T_SEQ * HD;
  const ushort* kh = kb + (size_t)h * T_SEQ * HD;
  const ushort* vh = vt + (size_t)h * HD * T_SEQ;

  bf16x8 qf[4];
#pragma unroll
  for (int st = 0; st < 4; st++)
    qf[st] = *(const bf16x8*)&qh[(size_t)(qbase + q31) * HD + st * 16 + 8 * hi];

  f32x16 acc0 = {}, acc1 = {};
  float mrow = -1e30f, lrow = 0.f;
  int qglob = qbase + q31;

  for (int ti = 0; ti < ntile; ti++) {
    int k0 = kstart + ti * 32;
    // QK^T: A=K rows, B=Q cols; two 2-deep chains instead of one 4-deep
    f32x16 c = {}, c2 = {};
    {
      bf16x8 kf0 = *(const bf16x8*)&kh[(size_t)(k0 + q31) * HD + 0  + 8 * hi];
      bf16x8 kf1 = *(const bf16x8*)&kh[(size_t)(k0 + q31) * HD + 16 + 8 * hi];
      bf16x8 kf2 = *(const bf16x8*)&kh[(size_t)(k0 + q31) * HD + 32 + 8 * hi];
      bf16x8 kf3 = *(const bf16x8*)&kh[(size_t)(k0 + q31) * HD + 48 + 8 * hi];
      c  = __builtin_amdgcn_mfma_f32_32x32x16_bf16(kf0, qf[0], c, 0, 0, 0);
      c2 = __builtin_amdgcn_mfma_f32_32x32x16_bf16(kf2, qf[2], c2, 0, 0, 0);
      c  = __builtin_amdgcn_mfma_f32_32x32x16_bf16(kf1, qf[1], c, 0, 0, 0);
      c2 = __builtin_amdgcn_mfma_f32_32x32x16_bf16(kf3, qf[3], c2, 0, 0, 0);
    }
    float p[16];
    float pmax = -1e30f;
#pragma unroll
    for (int r = 0; r < 16; r++) {
      float sc = (c[r] + c2[r]) * 0.12f;
      if (fin) {
        int key = k0 + (r & 3) + 8 * (r >> 2) + 4 * hi;
        if (key > qglob) sc = -1e30f;
      }
      p[r] = sc;
      pmax = fmaxf(pmax, sc);
    }
    pmax = fmaxf(pmax, __shfl_xor(pmax, 32, 64));
    float mn = fmaxf(mrow, pmax);
    float scl = __expf(mrow - mn);
    mrow = mn;
    float rs = 0.f;
#pragma unroll
    for (int r = 0; r < 16; r++) {
      p[r] = __expf(p[r] - mn);
      rs += p[r];
    }
    rs += __shfl_xor(rs, 32, 64);
    lrow = lrow * scl + rs;
#pragma unroll
    for (int r = 0; r < 16; r++) { acc0[r] *= scl; acc1[r] *= scl; }
    // pack P pairs (keys are adjacent for reg pairs 2j,2j+1):
    //   pw[0]=(4hi+0,4hi+1) pw[1]=(4hi+2,3) pw[2]=(8+4hi+0,1) pw[3]=(8+4hi+2,3)
    //   pw[4]=(16+4hi..) pw[5] pw[6]=(24+4hi..) pw[7]
    unsigned int pw[8];
#pragma unroll
    for (int j = 0; j < 8; j++)
      pw[j] = (unsigned int)f2bf(p[2 * j]) | ((unsigned int)f2bf(p[2 * j + 1]) << 16);
    // partner words via verified __shfl_xor(·,32)
    unsigned int sw[8];
#pragma unroll
    for (int j = 0; j < 8; j++)
      sw[j] = __shfl_xor(pw[j], 32, 64);
    // B-frag slot k = 8*hi + j needs key k0+8hi+j:
    //   hi=0: words {(0,1),(2,3),(4,5),(6,7)} = {pw0,pw1,sw0,sw1}
    //   hi=1: words {(8,9),(10,11),(12,13),(14,15)} = {sw2,sw3,pw2,pw3}
    u32x4 u0, u1;
    u0[0] = hi ? sw[2] : pw[0];
    u0[1] = hi ? sw[3] : pw[1];
    u0[2] = hi ? pw[2] : sw[0];
    u0[3] = hi ? pw[3] : sw[1];
    u1[0] = hi ? sw[6] : pw[4];
    u1[1] = hi ? sw[7] : pw[5];
    u1[2] = hi ? pw[6] : sw[4];
    u1[3] = hi ? pw[7] : sw[5];
    bf16x8 pb0 = __builtin_bit_cast(bf16x8, u0);   // keys k0 + 8hi + [0,8)
    bf16x8 pb1 = __builtin_bit_cast(bf16x8, u1);   // keys k0 + 16 + 8hi + [0,8)
    // PV: O^T[d][q] += V^T[d][k] * P[k][q]
    bf16x8 v00 = *(const bf16x8*)&vh[(size_t)q31 * T_SEQ + k0 + 8 * hi];
    bf16x8 v01 = *(const bf16x8*)&vh[(size_t)q31 * T_SEQ + k0 + 16 + 8 * hi];
    bf16x8 v10 = *(const bf16x8*)&vh[(size_t)(32 + q31) * T_SEQ + k0 + 8 * hi];
    bf16x8 v11 = *(const bf16x8*)&vh[(size_t)(32 + q31) * T_SEQ + k0 + 16 + 8 * hi];
    acc0 = __builtin_amdgcn_mfma_f32_32x32x16_bf16(v00, pb0, acc0, 0, 0, 0);
    acc0 = __builtin_amdgcn_mfma_f32_32x32x16_bf16(v01, pb1, acc0, 0, 0, 0);
    acc1 = __builtin_amdgcn_mfma_f32_32x32x16_bf16(v10, pb0, acc1, 0, 0, 0);
    acc1 = __builtin_amdgcn_mfma_f32_32x32x16_bf16(v11, pb1, acc1, 0, 0, 0);
  }
  // store partial record (unnormalized)
  ushort* rec = parts + (size_t)((h * 64 + qt) * 4 + ch) * 2176;
#pragma unroll
  for (int r = 0; r < 16; r++) {
    int d = (r & 3) + 8 * (r >> 2) + 4 * hi;
    rec[q31 * 64 + d]      = f2bf(acc0[r]);
    rec[q31 * 64 + 32 + d] = f2bf(acc1[r]);
  }
  if (!hi) {
    *(float*)((char*)rec + 4096 + q31 * 8)     = mrow;
    *(float*)((char*)rec + 4096 + q31 * 8 + 4) = lrow;
  }
}

// ---------- 4b) merge split-K partials -> bf16 attn output [t][h*64+d] ----------
__global__ __launch_bounds__(256) void attn_merge(const ushort* __restrict__ parts,
                                                  ushort* __restrict__ o) {
  int w = threadIdx.x >> 6, lane = threadIdx.x & 63;
  int t4 = blockIdx.x * 4 + w;
  int h = t4 >> 6, qt = t4 & 63;
  int nch = qt / 16 + 1;
  int qbase = qt * 32;
  const ushort* base = parts + (size_t)((h * 64 + qt) * 4) * 2176;
  for (int r = 0; r < 32; r++) {
    float mm[4], ll[4];
    float M = -1e30f;
#pragma unroll
    for (int i = 0; i < 4; i++) {
      if (i < nch) {
        mm[i] = *(const float*)((const char*)base + i * 4352 + 4096 + r * 8);
        ll[i] = *(const float*)((const char*)base + i * 4352 + 4096 + r * 8 + 4);
        M = fmaxf(M, mm[i]);
      }
    }
    float L = 0.f, ov = 0.f;
#pragma unroll
    for (int i = 0; i < 4; i++) {
      if (i < nch) {
        float wg = __expf(mm[i] - M);
        L += wg * ll[i];
        ov += wg * bf2f(base[i * 2176 + r * 64 + lane]);
      }
    }
    o[(size_t)(qbase + r) * DIM + h * HD + lane] = f2bf(ov / L);
  }
}

// ---------- 6) expmap(ref, y) ----------
__global__ void expmap_kernel(const float* __restrict__ y2,
                              const float* __restrict__ ref,
                              float* __restrict__ yout) {
  __shared__ float s4[4];
  int t = blockIdx.x;
  float xe[4], ve[4];
  float xn2 = 0.f, vn2 = 0.f, xv = 0.f;
#pragma unroll
  for (int i = 0; i < 4; i++) {
    int e = threadIdx.x + i * 256;
    float X = ref[(size_t)t * DIM + e];
    float V = y2[(size_t)t * DIM + e];
    xe[i] = X; ve[i] = V;
    xn2 += X * X; vn2 += V * V; xv += X * V;
  }
  xn2 = blockSum(xn2, s4);
  vn2 = blockSum(vn2, s4);
  xv  = blockSum(xv,  s4);
  float vn  = sqrtf(vn2);
  float sf  = 2.f / (1.f + xn2);
  float arg = sqrtf(fminf(fmaxf(0.5f * sf * vn2, 0.f), 8.f));
  float scl = tanhf(arg) / (vn + EPSF);
  float yn2 = scl * scl * vn2;
  float ip  = scl * xv;
  float A = 1.f + 2.f * ip + yn2;
  float B = (1.f - xn2) * scl;
  float den = fmaxf(1.f + 2.f * ip + xn2 * yn2, EPSF);
  float invden = 1.f / den;
#pragma unroll
  for (int i = 0; i < 4; i++)
    yout[(size_t)t * DIM + threadIdx.x + i * 256] = (A * xe[i] + B * ve[i]) * invden;
}

// ---------- launch ----------
extern "C" void kernel_launch(void* const* d_in, const int* in_sizes, int n_in,
                              void* d_out, int out_size, void* d_ws, size_t ws_size,
                              hipStream_t stream) {
  const float* x        = (const float*)d_in[0];
  const float* qkv_w    = (const float*)d_in[1];
  const float* c_proj_w = (const float*)d_in[2];
  float* out = (float*)d_out;
  char*  W   = (char*)d_ws;

  ushort* qkvw_bf   = (ushort*)(W);             // [0, 6MB)
  ushort* cprojw_bf = (ushort*)(W + 6  * MB);   // [6, 8MB)
  ushort* xhyp_bf   = (ushort*)(W + 8  * MB);   // [8, 12MB)  reused as attn out o
  float*  qkvf      = (float*) (W + 12 * MB);   // [12, 36MB)
  ushort* qbuf      = (ushort*)(W + 36 * MB);   // [36, 40MB)
  ushort* kbuf      = (ushort*)(W + 40 * MB);   // [40, 44MB)
  ushort* vtb       = (ushort*)(W + 44 * MB);   // [44, 48MB)
  ushort* parts     = (ushort*)(W + 12 * MB);   // over qkvf after it's consumed (17.8MB)
  ushort* obuf      = xhyp_bf;
  float*  y2        = qkvf;
  float*  ref       = out + (size_t)T_SEQ * DIM;

  cvt_kernel<<<1536, 256, 0, stream>>>(qkv_w, qkvw_bf, 393216);
  cvt_kernel<<<512, 256, 0, stream>>>(c_proj_w, cprojw_bf, 131072);
  logmap_kernel<<<T_SEQ, 256, 0, stream>>>(x, xhyp_bf, ref);
  gemm_bf16<<<dim3(HD3 / 128, T_SEQ / 128), 256, 0, stream>>>(xhyp_bf, qkvw_bf, qkvf, T_SEQ, HD3, DIM);
  rmsrot_kernel<<<dim3(T_SEQ, 4), 256, 0, stream>>>(qkvf, qbuf, kbuf);
  vtrans_kernel<<<dim3(T_SEQ / 64, NH), 256, 0, stream>>>(qkvf, vtb);
  attn_mfma<<<640, 256, 0, stream>>>(qbuf, kbuf, vtb, parts);
  attn_merge<<<256, 256, 0, stream>>>(parts, obuf);
  gemm_bf16<<<dim3(DIM / 128, T_SEQ / 128), 256, 0, stream>>>(obuf, cprojw_bf, y2, T_SEQ, DIM, DIM);
  expmap_kernel<<<T_SEQ, 256, 0, stream>>>(y2, ref, out);
}

// Round 7
// 151.499 us; speedup vs baseline: 1.3883x; 1.3883x over previous
//
#include <hip/hip_runtime.h>
#include <math.h>

#define T_SEQ 2048
#define DIM   1024
#define HD3   3072
#define NH    16
#define HD    64
#define EPSF  1e-4f
#define MB    1048576

typedef __attribute__((ext_vector_type(8))) short bf16x8;
typedef __attribute__((ext_vector_type(4))) float f32x4;
typedef __attribute__((ext_vector_type(16))) float f32x16;
typedef __attribute__((ext_vector_type(4))) unsigned int u32x4;

__device__ __forceinline__ ushort f2bf(float f) {
  unsigned int u = __float_as_uint(f);
  unsigned int r = (u + 0x7FFFu + ((u >> 16) & 1u)) >> 16;
  return (ushort)r;
}
__device__ __forceinline__ float bf2f(ushort u) {
  return __uint_as_float(((unsigned int)u) << 16);
}

#define GLOAD(gp, lp) __builtin_amdgcn_global_load_lds( \
    (const __attribute__((address_space(1))) unsigned int*)(gp), \
    (__attribute__((address_space(3))) unsigned int*)(lp), 16, 0, 0)

// ---------- helpers ----------
__device__ __forceinline__ float blockSum(float v, float* s4) {
#pragma unroll
  for (int o = 32; o > 0; o >>= 1) v += __shfl_xor(v, o, 64);
  __syncthreads();
  if ((threadIdx.x & 63) == 0) s4[threadIdx.x >> 6] = v;
  __syncthreads();
  return s4[0] + s4[1] + s4[2] + s4[3];
}

// ---------- 0) f32 -> bf16 convert ----------
__global__ void cvt_kernel(const float* __restrict__ src, ushort* __restrict__ dst, int n8) {
  int i = blockIdx.x * 256 + threadIdx.x;
  if (i >= n8) return;
  float4 a = ((const float4*)src)[i * 2];
  float4 b = ((const float4*)src)[i * 2 + 1];
  bf16x8 v;
  v[0] = f2bf(a.x); v[1] = f2bf(a.y); v[2] = f2bf(a.z); v[3] = f2bf(a.w);
  v[4] = f2bf(b.x); v[5] = f2bf(b.y); v[6] = f2bf(b.z); v[7] = f2bf(b.w);
  *(bf16x8*)(dst + (size_t)i * 8) = v;
}

// ---------- 1) logmap(ref, x) -> bf16 xhyp ; also emit ref (f32) ----------
__global__ void logmap_kernel(const float* __restrict__ x,
                              ushort* __restrict__ xhyp,
                              float* __restrict__ ref_out) {
  __shared__ float s4[4];
  int t = blockIdx.x;
  const float* xt = x + (size_t)t * DIM;
  float xe[4], re[4];
  float xn2 = 0.f, yn2 = 0.f, ip = 0.f;
#pragma unroll
  for (int i = 0; i < 4; i++) {
    int e = threadIdx.x + i * 256;
    float xv = xt[e];
    float rv = (t > 0) ? xt[e - DIM] : 0.f;
    xe[i] = xv; re[i] = rv;
    yn2 += xv * xv;
    xn2 += rv * rv;
    ip  -= rv * xv;
    ref_out[(size_t)t * DIM + e] = rv;
  }
  xn2 = blockSum(xn2, s4);
  yn2 = blockSum(yn2, s4);
  ip  = blockSum(ip,  s4);
  float a = 1.f + 2.f * ip + yn2;
  float b = 1.f - xn2;
  float den = fmaxf(1.f + 2.f * ip + xn2 * yn2, EPSF);
  float invden = 1.f / den;
  float mob[4];
  float mn2 = 0.f;
#pragma unroll
  for (int i = 0; i < 4; i++) {
    float m = (-a * re[i] + b * xe[i]) * invden;
    mob[i] = m;
    mn2 += m * m;
  }
  mn2 = blockSum(mn2, s4);
  float mn  = sqrtf(mn2);
  float sf  = 2.f / (1.f + xn2);
  float cf  = 2.f / (sf + EPSF);
  float arg = fminf(sqrtf(mn), 0.99f);
  float mult = cf * atanhf(arg) / (mn + EPSF);
#pragma unroll
  for (int i = 0; i < 4; i++)
    xhyp[(size_t)t * DIM + threadIdx.x + i * 256] = f2bf(mult * mob[i]);
}

// ---------- 2/5) C[M][N] = A[M][K] * W[N][K]^T  (bf16 MFMA, f32 out) ----------
__global__ __launch_bounds__(256) void gemm_bf16(const ushort* __restrict__ A,
                                                 const ushort* __restrict__ W,
                                                 float* __restrict__ C,
                                                 int M, int N, int K) {
  __shared__ ushort As[128 * 32];
  __shared__ ushort Bs[128 * 32];
  int tid = threadIdx.x;
  int lane = tid & 63, w = tid >> 6;
  int wr = w >> 1, wc = w & 1;
  int g = lane >> 4, cc = lane & 15;
  int bm = blockIdx.y * 128, bn = blockIdx.x * 128;
  f32x4 acc[4][4] = {};
  for (int kt = 0; kt < K; kt += 32) {
#pragma unroll
    for (int i = 0; i < 2; i++) {
      int ch = (w * 2 + i) * 64 + lane;
      int row = ch >> 2, c8 = (ch & 3) * 8;
      GLOAD(A + (size_t)(bm + row) * K + kt + c8, &As[(w * 2 + i) * 512]);
      GLOAD(W + (size_t)(bn + row) * K + kt + c8, &Bs[(w * 2 + i) * 512]);
    }
    __syncthreads();
    bf16x8 af[4], bfr[4];
#pragma unroll
    for (int m = 0; m < 4; m++)
      af[m] = *(const bf16x8*)&As[(wr * 64 + m * 16 + cc) * 32 + 8 * g];
#pragma unroll
    for (int n = 0; n < 4; n++)
      bfr[n] = *(const bf16x8*)&Bs[(wc * 64 + n * 16 + cc) * 32 + 8 * g];
#pragma unroll
    for (int m = 0; m < 4; m++)
#pragma unroll
      for (int n = 0; n < 4; n++)
        acc[m][n] = __builtin_amdgcn_mfma_f32_16x16x32_bf16(af[m], bfr[n], acc[m][n], 0, 0, 0);
    __syncthreads();
  }
#pragma unroll
  for (int m = 0; m < 4; m++)
#pragma unroll
    for (int n = 0; n < 4; n++)
#pragma unroll
      for (int j = 0; j < 4; j++)
        C[(size_t)(bm + wr * 64 + m * 16 + g * 4 + j) * N + bn + wc * 64 + n * 16 + cc] = acc[m][n][j];
}

// ---------- 3) RMS-norm + rotary -> bf16 q,k in [h][t][64] ----------
__global__ void rmsrot_kernel(const float* __restrict__ qkv,
                              ushort* __restrict__ qb,
                              ushort* __restrict__ kb) {
  int t = blockIdx.x;
  int w = threadIdx.x >> 6;
  int lane = threadIdx.x & 63;
  int h = blockIdx.y * 4 + w;
  const float* base = qkv + (size_t)t * HD3;
  float qv = base[h * HD + lane];
  float kv = base[DIM + h * HD + lane];
  float qs = qv * qv, ks = kv * kv;
#pragma unroll
  for (int o = 32; o > 0; o >>= 1) {
    qs += __shfl_xor(qs, o, 64);
    ks += __shfl_xor(ks, o, 64);
  }
  float qn = qv * rsqrtf(qs * (1.f / 64.f) + 1.1920929e-07f);
  float kn = kv * rsqrtf(ks * (1.f / 64.f) + 1.1920929e-07f);
  int j = lane & 31;
  float cth = 1.f, sth = 0.f;
  if (j < 16) {
    float freq = exp2f(-(10.f / 15.f) * (float)j);
    float th = (float)t * freq;
    cth = cosf(th);
    sth = sinf(th);
  }
  float qp = __shfl_xor(qn, 32, 64);
  float kp = __shfl_xor(kn, 32, 64);
  float sgn = (lane < 32) ? 1.f : -1.f;
  float qr = qn * cth + sgn * qp * sth;
  float kr = kn * cth + sgn * kp * sth;
  qb[((size_t)h * T_SEQ + t) * HD + lane] = f2bf(qr);
  kb[((size_t)h * T_SEQ + t) * HD + lane] = f2bf(kr);
}

// ---------- 3b) V transpose -> bf16 vT [h][64][T] ----------
__global__ void vtrans_kernel(const float* __restrict__ qkv, ushort* __restrict__ vt) {
  __shared__ ushort tile[64][68];
  int h = blockIdx.y, tt = blockIdx.x;
  int d = threadIdx.x & 63, tr = threadIdx.x >> 6;
#pragma unroll
  for (int i = 0; i < 16; i++) {
    int t = tt * 64 + tr + i * 4;
    tile[d][tr + i * 4] = f2bf(qkv[(size_t)t * HD3 + 2 * DIM + h * HD + d]);
  }
  __syncthreads();
  int td = threadIdx.x & 63, dr = threadIdx.x >> 6;
#pragma unroll
  for (int i = 0; i < 16; i++) {
    int dd = dr + i * 4;
    vt[((size_t)h * HD + dd) * T_SEQ + tt * 64 + td] = tile[dd][td];
  }
}

// ---------- 4) causal flash attention, swapped-operand 32x32 MFMA, no LDS ----------
// C[key][query]: col=lane&31=query, row=(reg&3)+8*(reg>>2)+4*(lane>>5)=key.
__global__ __launch_bounds__(256) void attn_mfma(const ushort* __restrict__ qb,
                                                 const ushort* __restrict__ kb,
                                                 const ushort* __restrict__ vt,
                                                 ushort* __restrict__ parts) {
  int lane = threadIdx.x & 63;
  int hi = lane >> 5;
  int q31 = lane & 31;
  int w = threadIdx.x >> 6;
  int tid = blockIdx.x * 4 + w;
  int h = tid / 160;
  int s = 159 - (tid % 160);      // heavy tasks first
  int qt, ch;
  if (s < 16)      { qt = s;                 ch = 0; }
  else if (s < 48) { qt = 16 + (s - 16) / 2; ch = (s - 16) % 2; }
  else if (s < 96) { qt = 32 + (s - 48) / 3; ch = (s - 48) % 3; }
  else             { qt = 48 + (s - 96) / 4; ch = (s - 96) % 4; }
  int qbase  = qt * 32;
  int kstart = ch * 512;
  int kend   = min(kstart + 512, qbase + 32);
  bool fin   = (kend == qbase + 32);
  int ntile  = (kend - kstart) >> 5;

  const ushort* qh = qb + (size_t)h * T_SEQ * HD;
  const ushort* kh = kb + (size_t)h * T_SEQ * HD;
  const ushort* vh = vt + (size_t)h * HD * T_SEQ;

  bf16x8 qf[4];
#pragma unroll
  for (int st = 0; st < 4; st++)
    qf[st] = *(const bf16x8*)&qh[(size_t)(qbase + q31) * HD + st * 16 + 8 * hi];

  f32x16 acc0 = {}, acc1 = {};
  float mrow = -1e30f, lrow = 0.f;
  int qglob = qbase + q31;

  for (int ti = 0; ti < ntile; ti++) {
    int k0 = kstart + ti * 32;
    // QK^T: A=K rows, B=Q cols; two 2-deep chains
    f32x16 c = {}, c2 = {};
    {
      bf16x8 kf0 = *(const bf16x8*)&kh[(size_t)(k0 + q31) * HD + 0  + 8 * hi];
      bf16x8 kf1 = *(const bf16x8*)&kh[(size_t)(k0 + q31) * HD + 16 + 8 * hi];
      bf16x8 kf2 = *(const bf16x8*)&kh[(size_t)(k0 + q31) * HD + 32 + 8 * hi];
      bf16x8 kf3 = *(const bf16x8*)&kh[(size_t)(k0 + q31) * HD + 48 + 8 * hi];
      c  = __builtin_amdgcn_mfma_f32_32x32x16_bf16(kf0, qf[0], c, 0, 0, 0);
      c2 = __builtin_amdgcn_mfma_f32_32x32x16_bf16(kf2, qf[2], c2, 0, 0, 0);
      c  = __builtin_amdgcn_mfma_f32_32x32x16_bf16(kf1, qf[1], c, 0, 0, 0);
      c2 = __builtin_amdgcn_mfma_f32_32x32x16_bf16(kf3, qf[3], c2, 0, 0, 0);
    }
    float p[16];
    float pmax = -1e30f;
#pragma unroll
    for (int r = 0; r < 16; r++) {
      float sc = (c[r] + c2[r]) * 0.12f;
      if (fin) {
        int key = k0 + (r & 3) + 8 * (r >> 2) + 4 * hi;
        if (key > qglob) sc = -1e30f;
      }
      p[r] = sc;
      pmax = fmaxf(pmax, sc);
    }
    pmax = fmaxf(pmax, __shfl_xor(pmax, 32, 64));
    float mn = fmaxf(mrow, pmax);
    float scl = __expf(mrow - mn);
    mrow = mn;
    float rs = 0.f;
#pragma unroll
    for (int r = 0; r < 16; r++) {
      p[r] = __expf(p[r] - mn);
      rs += p[r];
    }
    rs += __shfl_xor(rs, 32, 64);
    lrow = lrow * scl + rs;
#pragma unroll
    for (int r = 0; r < 16; r++) { acc0[r] *= scl; acc1[r] *= scl; }
    // pack P pairs; partner words via __shfl_xor(·,32)
    unsigned int pw[8];
#pragma unroll
    for (int j = 0; j < 8; j++)
      pw[j] = (unsigned int)f2bf(p[2 * j]) | ((unsigned int)f2bf(p[2 * j + 1]) << 16);
    unsigned int sw[8];
#pragma unroll
    for (int j = 0; j < 8; j++)
      sw[j] = __shfl_xor(pw[j], 32, 64);
    u32x4 u0, u1;
    u0[0] = hi ? sw[2] : pw[0];
    u0[1] = hi ? sw[3] : pw[1];
    u0[2] = hi ? pw[2] : sw[0];
    u0[3] = hi ? pw[3] : sw[1];
    u1[0] = hi ? sw[6] : pw[4];
    u1[1] = hi ? sw[7] : pw[5];
    u1[2] = hi ? pw[6] : sw[4];
    u1[3] = hi ? pw[7] : sw[5];
    bf16x8 pb0 = __builtin_bit_cast(bf16x8, u0);   // keys k0 + 8hi + [0,8)
    bf16x8 pb1 = __builtin_bit_cast(bf16x8, u1);   // keys k0 + 16 + 8hi + [0,8)
    // PV: O^T[d][q] += V^T[d][k] * P[k][q]
    bf16x8 v00 = *(const bf16x8*)&vh[(size_t)q31 * T_SEQ + k0 + 8 * hi];
    bf16x8 v01 = *(const bf16x8*)&vh[(size_t)q31 * T_SEQ + k0 + 16 + 8 * hi];
    bf16x8 v10 = *(const bf16x8*)&vh[(size_t)(32 + q31) * T_SEQ + k0 + 8 * hi];
    bf16x8 v11 = *(const bf16x8*)&vh[(size_t)(32 + q31) * T_SEQ + k0 + 16 + 8 * hi];
    acc0 = __builtin_amdgcn_mfma_f32_32x32x16_bf16(v00, pb0, acc0, 0, 0, 0);
    acc0 = __builtin_amdgcn_mfma_f32_32x32x16_bf16(v01, pb1, acc0, 0, 0, 0);
    acc1 = __builtin_amdgcn_mfma_f32_32x32x16_bf16(v10, pb0, acc1, 0, 0, 0);
    acc1 = __builtin_amdgcn_mfma_f32_32x32x16_bf16(v11, pb1, acc1, 0, 0, 0);
  }
  // store partial record (unnormalized)
  ushort* rec = parts + (size_t)((h * 64 + qt) * 4 + ch) * 2176;
#pragma unroll
  for (int r = 0; r < 16; r++) {
    int d = (r & 3) + 8 * (r >> 2) + 4 * hi;
    rec[q31 * 64 + d]      = f2bf(acc0[r]);
    rec[q31 * 64 + 32 + d] = f2bf(acc1[r]);
  }
  if (!hi) {
    *(float*)((char*)rec + 4096 + q31 * 8)     = mrow;
    *(float*)((char*)rec + 4096 + q31 * 8 + 4) = lrow;
  }
}

// ---------- 4b) merge split-K partials -> bf16 attn output [t][h*64+d] ----------
// one wave per (h, qt, row): 32768 waves, no serial row loop.
__global__ __launch_bounds__(256) void attn_merge(const ushort* __restrict__ parts,
                                                  ushort* __restrict__ o) {
  int w = threadIdx.x >> 6, lane = threadIdx.x & 63;
  int idx = blockIdx.x * 4 + w;       // (h*64 + qt)*32 + r
  int r = idx & 31;
  int rec_i = idx >> 5;
  int qt = rec_i & 63, h = rec_i >> 6;
  int nch = qt / 16 + 1;
  const ushort* base = parts + (size_t)rec_i * 4 * 2176;
  float mm[4], ll[4];
  float M = -1e30f;
#pragma unroll
  for (int i = 0; i < 4; i++) {
    if (i < nch) {
      mm[i] = *(const float*)((const char*)base + i * 4352 + 4096 + r * 8);
      ll[i] = *(const float*)((const char*)base + i * 4352 + 4096 + r * 8 + 4);
      M = fmaxf(M, mm[i]);
    }
  }
  float L = 0.f, ov = 0.f;
#pragma unroll
  for (int i = 0; i < 4; i++) {
    if (i < nch) {
      float wg = __expf(mm[i] - M);
      L += wg * ll[i];
      ov += wg * bf2f(base[i * 2176 + r * 64 + lane]);
    }
  }
  o[(size_t)(qt * 32 + r) * DIM + h * HD + lane] = f2bf(ov / L);
}

// ---------- 6) expmap(ref, y) ----------
__global__ void expmap_kernel(const float* __restrict__ y2,
                              const float* __restrict__ ref,
                              float* __restrict__ yout) {
  __shared__ float s4[4];
  int t = blockIdx.x;
  float xe[4], ve[4];
  float xn2 = 0.f, vn2 = 0.f, xv = 0.f;
#pragma unroll
  for (int i = 0; i < 4; i++) {
    int e = threadIdx.x + i * 256;
    float X = ref[(size_t)t * DIM + e];
    float V = y2[(size_t)t * DIM + e];
    xe[i] = X; ve[i] = V;
    xn2 += X * X; vn2 += V * V; xv += X * V;
  }
  xn2 = blockSum(xn2, s4);
  vn2 = blockSum(vn2, s4);
  xv  = blockSum(xv,  s4);
  float vn  = sqrtf(vn2);
  float sf  = 2.f / (1.f + xn2);
  float arg = sqrtf(fminf(fmaxf(0.5f * sf * vn2, 0.f), 8.f));
  float scl = tanhf(arg) / (vn + EPSF);
  float yn2 = scl * scl * vn2;
  float ip  = scl * xv;
  float A = 1.f + 2.f * ip + yn2;
  float B = (1.f - xn2) * scl;
  float den = fmaxf(1.f + 2.f * ip + xn2 * yn2, EPSF);
  float invden = 1.f / den;
#pragma unroll
  for (int i = 0; i < 4; i++)
    yout[(size_t)t * DIM + threadIdx.x + i * 256] = (A * xe[i] + B * ve[i]) * invden;
}

// ---------- launch ----------
extern "C" void kernel_launch(void* const* d_in, const int* in_sizes, int n_in,
                              void* d_out, int out_size, void* d_ws, size_t ws_size,
                              hipStream_t stream) {
  const float* x        = (const float*)d_in[0];
  const float* qkv_w    = (const float*)d_in[1];
  const float* c_proj_w = (const float*)d_in[2];
  float* out = (float*)d_out;
  char*  W   = (char*)d_ws;

  ushort* qkvw_bf   = (ushort*)(W);             // [0, 6MB)
  ushort* cprojw_bf = (ushort*)(W + 6  * MB);   // [6, 8MB)
  ushort* xhyp_bf   = (ushort*)(W + 8  * MB);   // [8, 12MB)  reused as attn out o
  float*  qkvf      = (float*) (W + 12 * MB);   // [12, 36MB)
  ushort* qbuf      = (ushort*)(W + 36 * MB);   // [36, 40MB)
  ushort* kbuf      = (ushort*)(W + 40 * MB);   // [40, 44MB)
  ushort* vtb       = (ushort*)(W + 44 * MB);   // [44, 48MB)
  ushort* parts     = (ushort*)(W + 12 * MB);   // over qkvf after it's consumed (17.8MB)
  ushort* obuf      = xhyp_bf;
  float*  y2        = qkvf;
  float*  ref       = out + (size_t)T_SEQ * DIM;

  cvt_kernel<<<1536, 256, 0, stream>>>(qkv_w, qkvw_bf, 393216);
  cvt_kernel<<<512, 256, 0, stream>>>(c_proj_w, cprojw_bf, 131072);
  logmap_kernel<<<T_SEQ, 256, 0, stream>>>(x, xhyp_bf, ref);
  gemm_bf16<<<dim3(HD3 / 128, T_SEQ / 128), 256, 0, stream>>>(xhyp_bf, qkvw_bf, qkvf, T_SEQ, HD3, DIM);
  rmsrot_kernel<<<dim3(T_SEQ, 4), 256, 0, stream>>>(qkvf, qbuf, kbuf);
  vtrans_kernel<<<dim3(T_SEQ / 64, NH), 256, 0, stream>>>(qkvf, vtb);
  attn_mfma<<<640, 256, 0, stream>>>(qbuf, kbuf, vtb, parts);
  attn_merge<<<8192, 256, 0, stream>>>(parts, obuf);
  gemm_bf16<<<dim3(DIM / 128, T_SEQ / 128), 256, 0, stream>>>(obuf, cprojw_bf, y2, T_SEQ, DIM, DIM);
  expmap_kernel<<<T_SEQ, 256, 0, stream>>>(y2, ref, out);
}